// Round 11
// baseline (202.937 us; speedup 1.0000x reference)
//
#include <hip/hip_runtime.h>
#include <hip/hip_bf16.h>
#include <stdint.h>

// B=2, SQ=2048, SE=2048, SKV=4096, H=1024, NH=16, HD=64
// fp32 in/out; internal compute bf16 MFMA.

typedef __attribute__((ext_vector_type(8))) short short8;
typedef __attribute__((ext_vector_type(4))) float f32x4;
typedef __attribute__((ext_vector_type(4))) unsigned short us4;

// may_alias types for LDS handoffs (written as one type, read as another):
// without them TBAA lets the scheduler hoist ds_reads above ds_writes (R3 lesson).
typedef __attribute__((ext_vector_type(8), may_alias)) short short8a;
typedef __attribute__((ext_vector_type(4), may_alias)) float f32x4a;
typedef __attribute__((may_alias)) unsigned long long u64a;
typedef __attribute__((may_alias)) float floata;

#define MEMBAR() asm volatile("" ::: "memory")
#define DEV static __device__ __forceinline__

DEV unsigned short f2bf(float f) {
  unsigned int u = __builtin_bit_cast(unsigned int, f);
  u += 0x7fffu + ((u >> 16) & 1u);   // RNE
  return (unsigned short)(u >> 16);
}

DEV float exp2_(float x) {
#if __has_builtin(__builtin_amdgcn_exp2f)
  return __builtin_amdgcn_exp2f(x);
#else
  float r; asm("v_exp_f32 %0, %1" : "=v"(r) : "v"(x)); return r;
#endif
}

DEV unsigned int cvtpk_bf16(float lo, float hi) {
  unsigned int r;
  asm("v_cvt_pk_bf16_f32 %0, %1, %2" : "=v"(r) : "v"(lo), "v"(hi));
  return r;
}

DEV void g2lds16(const void* g, void* l) {
  __builtin_amdgcn_global_load_lds((const __attribute__((address_space(1))) void*)g,
                                   (__attribute__((address_space(3))) void*)l, 16, 0, 0);
}

// ---------- input conversion: all_hs = concat(hidden, encoder) -> bf16 ----------
__global__ __launch_bounds__(256) void convert_allhs(const float* __restrict__ hid,
                                                     const float* __restrict__ enc,
                                                     unsigned short* __restrict__ ah) {
  int idx = blockIdx.x * 256 + threadIdx.x;
  const int perB = 4096 * 256;
  int b = idx / perB, r = idx - b * perB;
  int s = r >> 8, c4 = r & 255;
  const float* srcrow = (s < 2048) ? hid + (size_t)(b * 2048 + s) * 1024
                                   : enc + (size_t)(b * 2048 + (s - 2048)) * 1024;
  f32x4 v = *(const f32x4*)(srcrow + c4 * 4);
  us4 o;
  o[0] = f2bf(v[0]); o[1] = f2bf(v[1]); o[2] = f2bf(v[2]); o[3] = f2bf(v[3]);
  *(us4*)(ah + (size_t)idx * 4) = o;
}

// ---------- mask premultiply by log2(e) ----------
__global__ __launch_bounds__(256) void premul_mask(const float* __restrict__ m,
                                                   float* __restrict__ o) {
  int i = blockIdx.x * 256 + threadIdx.x;
  o[i] = m[i] * 1.4426950408889634f;
}

// ---------- merged weight transpose: Wt[n][k] = bf16(W[k][n]) for Wq,Wk,Wv ----------
__global__ __launch_bounds__(256) void transpose_w3(const float* __restrict__ Wq,
                                                    const float* __restrict__ Wk,
                                                    const float* __restrict__ Wv,
                                                    unsigned short* __restrict__ WtBase) {
  __shared__ unsigned short t[64][65];
  const int z = blockIdx.z;
  const float* W = (z == 0) ? Wq : (z == 1) ? Wk : Wv;
  unsigned short* Wt = WtBase + (size_t)z * 1048576;
  int k0 = blockIdx.y * 64, n0 = blockIdx.x * 64;
  int tid = threadIdx.x;
#pragma unroll
  for (int rep = 0; rep < 16; rep++) {
    int idx = rep * 256 + tid;
    int kk = idx >> 6, nn = idx & 63;
    t[kk][nn] = f2bf(W[(size_t)(k0 + kk) * 1024 + n0 + nn]);
  }
  __syncthreads();
#pragma unroll
  for (int rep = 0; rep < 16; rep++) {
    int idx = rep * 256 + tid;
    int nn = idx >> 6, kk = idx & 63;
    Wt[(size_t)(n0 + nn) * 1024 + k0 + kk] = t[kk][nn];
  }
}

// ---------- merged NT GEMM: Q + K + V projections in ONE 1280-block dispatch ----------
__global__ __launch_bounds__(256) void gemm_all(const unsigned short* __restrict__ WTQ,
                                                const unsigned short* __restrict__ WTK,
                                                const unsigned short* __restrict__ WTV,
                                                const unsigned short* __restrict__ AH,
                                                const float* __restrict__ bq,
                                                const float* __restrict__ bk,
                                                const float* __restrict__ bv,
                                                unsigned short* __restrict__ Qout,
                                                unsigned short* __restrict__ Kout,
                                                unsigned short* __restrict__ Vout,
                                                float qscale) {
  __shared__ unsigned short ldsA[128 * 32];
  __shared__ unsigned short ldsB[128 * 32];

  // bijective XCD chunking over 1280 tiles (1280 % 8 == 0)
  int id = blockIdx.x;
  int f2 = (id & 7) * 160 + (id >> 3);

  const unsigned short *A, *Bm;
  const float* bias;
  unsigned short* outb;
  int S, mode, r0, c0;
  float osc = 1.0f;
  if (f2 < 256) {                       // Q: c 16 x r 8 x b 2
    int t = f2;
    int b = t >> 7; t &= 127;
    c0 = (t & 15) * 128; r0 = (t >> 4) * 128;
    A = WTQ; Bm = AH + (size_t)b * 4194304; bias = bq;
    outb = Qout + (size_t)b * 2097152; S = 2048; mode = 0; osc = qscale;
  } else if (f2 < 768) {                // K: c 32 x r 8 x b 2
    int t = f2 - 256;
    int b = t >> 8; t &= 255;
    c0 = (t & 31) * 128; r0 = (t >> 5) * 128;
    A = WTK; Bm = AH + (size_t)b * 4194304; bias = bk;
    outb = Kout + (size_t)b * 4194304; S = 4096; mode = 0;
  } else {                              // V: c 8 x r 32 x b 2
    int t = f2 - 768;
    int b = t >> 8; t &= 255;
    c0 = (t & 7) * 128; r0 = (t >> 3) * 128;
    A = AH + (size_t)b * 4194304; Bm = WTV; bias = bv;
    outb = Vout + (size_t)b * 4194304; S = 4096; mode = 1;
  }

  const int tid = threadIdx.x, w = tid >> 6, l = tid & 63;
  const int wr = w >> 1, wc = w & 1;
  const int lrow = l >> 2, lk = (l & 3) * 8;
  const int lc = l & 15, g = l >> 4;

  f32x4 acc[4][4];
#pragma unroll
  for (int i = 0; i < 4; i++)
#pragma unroll
    for (int j = 0; j < 4; j++) acc[i][j] = (f32x4){0.f, 0.f, 0.f, 0.f};

  for (int k0 = 0; k0 < 1024; k0 += 32) {
#pragma unroll
    for (int t = 0; t < 2; t++) {
      const int tt = w * 2 + t;
      g2lds16(A + (size_t)(r0 + tt * 16 + lrow) * 1024 + k0 + lk, (char*)ldsA + tt * 1024);
      g2lds16(Bm + (size_t)(c0 + tt * 16 + lrow) * 1024 + k0 + lk, (char*)ldsB + tt * 1024);
    }
    __syncthreads();
    short8 af[4], bf[4];
#pragma unroll
    for (int f = 0; f < 4; f++) {
      af[f] = *(const short8*)((const char*)ldsA + (wr * 64 + f * 16 + lc) * 64 + g * 16);
      bf[f] = *(const short8*)((const char*)ldsB + (wc * 64 + f * 16 + lc) * 64 + g * 16);
    }
#pragma unroll
    for (int fr = 0; fr < 4; fr++)
#pragma unroll
      for (int fc = 0; fc < 4; fc++)
        acc[fr][fc] = __builtin_amdgcn_mfma_f32_16x16x32_bf16(af[fr], bf[fc], acc[fr][fc], 0, 0, 0);
    __syncthreads();
  }

#pragma unroll
  for (int fr = 0; fr < 4; fr++) {
    int rb = r0 + wr * 64 + fr * 16 + g * 4;
    float bv4[4];
    if (mode == 0) {
#pragma unroll
      for (int i = 0; i < 4; i++) bv4[i] = bias[rb + i];
    }
#pragma unroll
    for (int fc = 0; fc < 4; fc++) {
      int c = c0 + wc * 64 + fc * 16 + lc;
      float bc = (mode == 0) ? 0.f : bias[c];
      us4 pk;
#pragma unroll
      for (int i = 0; i < 4; i++) {
        float v = (acc[fr][fc][i] + (mode == 0 ? bv4[i] : bc)) * osc;
        pk[i] = f2bf(v);
      }
      size_t addr;
      if (mode == 0) addr = ((size_t)(rb >> 6) * S + c) * 64 + (rb & 63);
      else           addr = (size_t)c * S + rb;
      *(us4*)(outb + addr) = pk;
    }
  }
}

// ---------- flash attention v11: 32q/wave + kh-split, 32-kv tiles, 24KB LDS ----------
// R9 lesson: 48KB LDS -> 2 blocks/CU killed the 32q/wave win. R10 lesson: intra-wave
// LDS WAR reuse races. v11: shrink the KV TILE to 32 kv instead of the P buffer:
// K tile [32kv][128B]=4KB, V tile [64d][64B]=4KB per kh; plds 4 waves x 2 c2 x 1KB
// (separate c2 regions, R9-proven parallel handoff). Total 24576B -> 4 blocks/CU.
// Same LDS-traffic-per-output as R9 (the efficiency win), at R8's footprint.
__global__ __launch_bounds__(256) void attn_kernel(const unsigned short* __restrict__ Q,
                                                   const unsigned short* __restrict__ K,
                                                   const unsigned short* __restrict__ Vt,
                                                   const float* __restrict__ mask2,
                                                   float* __restrict__ out) {
  __shared__ __align__(16) char ldsAll[24576];
  // [0,8192): K tiles, kh*4096      [32 kv][128B rows]
  // [8192,16384): V tiles, kh*4096  [64 d][64B rows]
  // [16384,24576): P staging, wave*2048 + c2*1024  [16 q][64B rows]

  // XCD-chunked swizzle (T1)
  int flat = blockIdx.x + 32 * (blockIdx.y + 16 * blockIdx.z);   // 0..1023
  int xc = flat & 7, tt = flat >> 3;                             // tt: 0..127
  int f2 = xc * 64 + (tt & 63) + (tt >> 6) * 512;
  const int qt = f2 & 31, h = (f2 >> 5) & 15, b = f2 >> 9;

  const int tid = threadIdx.x, w = tid >> 6, l = tid & 63;
  const int rg = w & 1, kh = w >> 1;
  const int lc = l & 15, g = l >> 4;

  const unsigned short* Qb = Q + ((size_t)(b * 16 + h) * 2048) * 64;
  const unsigned short* Kb = K + ((size_t)((b * 16 + h) * 4096 + kh * 2048)) * 64;
  const unsigned short* Vb = Vt + ((size_t)(b * 16 + h) * 64) * 4096 + kh * 2048;
  const float* mk = mask2 + (size_t)b * 4096 + kh * 2048;
  const int sq0 = qt * 64 + rg * 32;

  // K staging: kh-pair stages 32 rows x 128B. wave rg: rows rg*16 + c*8 + srow;
  // LDS slot j=(l&7) holds global chunk j^(row&7), row&7 = srow.
  const int srow = l >> 3;
  const int kchunk = (l & 7) ^ srow;
  // V staging: 64 d-rows x 64B. wave rg: d = rg*32 + c*16 + (l>>2); slot j=(l&3)
  // holds global chunk j^key(d), key(d) = (d&3)^((d>>2)&3) = ((l>>2)^(l>>4))&3.
  const int vkey_s = ((l >> 2) ^ (l >> 4)) & 3;
  const int vchunk = (l & 3) ^ vkey_s;
  // read-side key for V and P (64B rows, row index = d or q with row&3 = lc&3):
  const int key4 = ((lc & 3) ^ (lc >> 2)) & 3;

  short8 qf[2][2];
#pragma unroll
  for (int c2 = 0; c2 < 2; c2++)
#pragma unroll
    for (int hh = 0; hh < 2; hh++)
      qf[c2][hh] = *(const short8*)(Qb + (size_t)(sq0 + c2 * 16 + lc) * 64 + hh * 32 + g * 8);

  short8 ones;
#pragma unroll
  for (int i = 0; i < 8; i++) ones[i] = (short)0x3f80;

  f32x4 ctx[2][4];
#pragma unroll
  for (int c2 = 0; c2 < 2; c2++)
#pragma unroll
    for (int df = 0; df < 4; df++) ctx[c2][df] = (f32x4){0.f, 0.f, 0.f, 0.f};
  f32x4 lsacc[2];
  lsacc[0] = (f32x4){0.f, 0.f, 0.f, 0.f};
  lsacc[1] = (f32x4){0.f, 0.f, 0.f, 0.f};

  char* kbase = ldsAll + kh * 4096;
  char* vbase = ldsAll + 8192 + kh * 4096;
  char* pwave = ldsAll + 16384 + w * 2048;

  // ---- stage tile 0 via regs ----
  {
    short8 kreg[2], vreg[2];
#pragma unroll
    for (int c = 0; c < 2; c++) {
      int kr = rg * 16 + c * 8 + srow;
      kreg[c] = *(const short8*)(Kb + (size_t)kr * 64 + kchunk * 8);
      int d = rg * 32 + c * 16 + (l >> 2);
      vreg[c] = *(const short8*)(Vb + (size_t)d * 4096 + vchunk * 8);
    }
#pragma unroll
    for (int c = 0; c < 2; c++) {
      int kr = rg * 16 + c * 8 + srow;
      *(short8a*)(kbase + kr * 128 + (l & 7) * 16) = kreg[c];
      int d = rg * 32 + c * 16 + (l >> 2);
      *(short8a*)(vbase + d * 64 + (l & 3) * 16) = vreg[c];
    }
  }
  __syncthreads();

  for (int t = 0; t < 64; t++) {
    const int s0 = t * 32;

    // mask loads FIRST (oldest vmcnt slots): their wait leaves the prefetch in flight
    f32x4 mvv[2];
#pragma unroll
    for (int f = 0; f < 2; f++)
      mvv[f] = *(const f32x4*)(mk + s0 + f * 16 + g * 4);

    // ---- issue reg-prefetch of tile t+1 (lands during compute below) ----
    short8 kreg[2], vreg[2];
    if (t < 63) {
#pragma unroll
      for (int c = 0; c < 2; c++) {
        int kr = rg * 16 + c * 8 + srow;
        kreg[c] = *(const short8*)(Kb + (size_t)(s0 + 32 + kr) * 64 + kchunk * 8);
        int d = rg * 32 + c * 16 + (l >> 2);
        vreg[c] = *(const short8*)(Vb + (size_t)d * 4096 + (s0 + 32) + vchunk * 8);
      }
    }

    // ---- QK^T (K frags read once, both c2) ; P = exp2(sc) -> per-c2 LDS region ----
#pragma unroll
    for (int f = 0; f < 2; f++) {
      short8 k0 = *(const short8*)(kbase + (f * 16 + lc) * 128 + (((0 + g) ^ (lc & 7)) << 4));
      short8 k1 = *(const short8*)(kbase + (f * 16 + lc) * 128 + (((4 + g) ^ (lc & 7)) << 4));
#pragma unroll
      for (int c2 = 0; c2 < 2; c2++) {
        f32x4 z = __builtin_amdgcn_mfma_f32_16x16x32_bf16(k0, qf[c2][0], mvv[f], 0, 0, 0);
        z = __builtin_amdgcn_mfma_f32_16x16x32_bf16(k1, qf[c2][1], z, 0, 0, 0);
        unsigned int lo = cvtpk_bf16(exp2_(z[0]), exp2_(z[1]));
        unsigned int hi = cvtpk_bf16(exp2_(z[2]), exp2_(z[3]));
        // P^T[q=lc][kv] row 64B; chunk = f*2 + (g>>1), inner 8B = g&1; XOR key4
        int addr = lc * 64 + (((f * 2 + (g >> 1)) ^ key4) << 4) + (g & 1) * 8;
        *(u64a*)(pwave + c2 * 1024 + addr) = ((unsigned long long)hi << 32) | lo;
      }
    }

    MEMBAR();  // P writes ordered before the pfrag reads below

    // ---- PV: ctx^T += V^T * P^T (V frags read once, both c2) ----
    short8 pfrag[2];
#pragma unroll
    for (int c2 = 0; c2 < 2; c2++)
      pfrag[c2] = (short8)*(const short8a*)(pwave + c2 * 1024 + lc * 64 + (((g ^ key4)) << 4));
#pragma unroll
    for (int df = 0; df < 4; df++) {
      short8 vf = *(const short8*)(vbase + (df * 16 + lc) * 64 + ((g ^ key4) << 4));
#pragma unroll
      for (int c2 = 0; c2 < 2; c2++)
        ctx[c2][df] = __builtin_amdgcn_mfma_f32_16x16x32_bf16(vf, pfrag[c2], ctx[c2][df], 0, 0, 0);
    }
#pragma unroll
    for (int c2 = 0; c2 < 2; c2++)
      lsacc[c2] = __builtin_amdgcn_mfma_f32_16x16x32_bf16(ones, pfrag[c2], lsacc[c2], 0, 0, 0);

    __syncthreads();   // all waves done reading LDS tile t

    // ---- write tile t+1 into LDS (vmcnt wait here, after full compute cover) ----
    if (t < 63) {
#pragma unroll
      for (int c = 0; c < 2; c++) {
        int kr = rg * 16 + c * 8 + srow;
        *(short8a*)(kbase + kr * 128 + (l & 7) * 16) = kreg[c];
        int d = rg * 32 + c * 16 + (l >> 2);
        *(short8a*)(vbase + d * 64 + (l & 3) * 16) = vreg[c];
      }
      __syncthreads();  // tile t+1 visible
    }
  }

  // ---- merge the kh halves (no-max softmax: ctx and ls are raw sums) ----
  float* mC = (float*)&ldsAll[0];        // 64 rows x 64 d fp32 = 16KB (K+V regions, reads done)
  float* lB = (float*)&ldsAll[16384];    // 64 fp32 (P region, reads done)
  if (kh == 1) {
#pragma unroll
    for (int c2 = 0; c2 < 2; c2++) {
      int row = rg * 32 + c2 * 16 + lc;
#pragma unroll
      for (int df = 0; df < 4; df++) {
        int slot = (df * 4 + g) ^ lc;   // 2 lanes/bank -> conflict-free
        *(f32x4a*)(mC + row * 64 + slot * 4) = ctx[c2][df];
      }
      if (g == 0) *(floata*)(lB + row) = lsacc[c2][0];
    }
  }
  __syncthreads();
  if (kh == 0) {
#pragma unroll
    for (int c2 = 0; c2 < 2; c2++) {
      int row = rg * 32 + c2 * 16 + lc;
      float ls = lsacc[c2][0] + *(const floata*)(lB + row);
      float inv = 1.f / ls;
      size_t orow = (size_t)(b * 2048 + qt * 64 + row);
#pragma unroll
      for (int df = 0; df < 4; df++) {
        int slot = (df * 4 + g) ^ lc;
        f32x4 o = (ctx[c2][df] + *(const f32x4a*)(mC + row * 64 + slot * 4)) * inv;
        *(f32x4*)(out + orow * 1024 + h * 64 + df * 16 + g * 4) = o;
      }
    }
  }
}

// ---------- launcher ----------
extern "C" void kernel_launch(void* const* d_in, const int* in_sizes, int n_in,
                              void* d_out, int out_size, void* d_ws, size_t ws_size,
                              hipStream_t stream) {
  const float* hid = (const float*)d_in[0];
  const float* enc = (const float*)d_in[1];
  const float* mask = (const float*)d_in[2];
  const float* Wq = (const float*)d_in[3];
  const float* bq = (const float*)d_in[4];
  const float* Wk = (const float*)d_in[5];
  const float* bk = (const float*)d_in[6];
  const float* Wv = (const float*)d_in[7];
  const float* bv = (const float*)d_in[8];

  unsigned short* ws = (unsigned short*)d_ws;
  unsigned short* WTQ = ws;                    // 1M elems (WTQ/WTK/WTV contiguous)
  unsigned short* WTK = ws + 1048576;          // 1M
  unsigned short* WTV = ws + 2097152;          // 1M
  unsigned short* AH  = ws + 3145728;          // 8M  [B][4096][1024]
  unsigned short* Qb  = ws + 11534336;         // 4M  [B][16][2048][64]
  unsigned short* Kb  = ws + 15728640;         // 8M  [B][16][4096][64]
  unsigned short* VT  = ws + 24117248;         // 8M  [B][16][64][4096]
  float* mask2 = (float*)(ws + 32505856);      // 8192 fp32

  const float QSCALE = 0.18033688011112042f;   // 0.125 * log2(e), folded into Q projection

  convert_allhs<<<8192, 256, 0, stream>>>(hid, enc, AH);
  premul_mask<<<32, 256, 0, stream>>>(mask, mask2);
  transpose_w3<<<dim3(16, 16, 3), 256, 0, stream>>>(Wq, Wk, Wv, WTQ);

  gemm_all<<<1280, 256, 0, stream>>>(WTQ, WTK, WTV, AH, bq, bk, bv, Qb, Kb, VT, QSCALE);

  attn_kernel<<<dim3(32, 16, 2), 256, 0, stream>>>(Qb, Kb, VT, mask2, (float*)d_out);
}

// Round 13
// 191.375 us; speedup vs baseline: 1.0604x; 1.0604x over previous
//
#include <hip/hip_runtime.h>
#include <hip/hip_bf16.h>
#include <stdint.h>

// B=2, SQ=2048, SE=2048, SKV=4096, H=1024, NH=16, HD=64
// fp32 in/out; internal compute bf16 MFMA.

typedef __attribute__((ext_vector_type(8))) short short8;
typedef __attribute__((ext_vector_type(4))) float f32x4;
typedef __attribute__((ext_vector_type(16))) float f32x16;
typedef __attribute__((ext_vector_type(4))) unsigned short us4;
typedef __attribute__((ext_vector_type(4))) unsigned int u32x4;

// may_alias types for LDS handoffs (R3 lesson: TBAA reorder).
typedef __attribute__((ext_vector_type(8), may_alias)) short short8a;
typedef __attribute__((ext_vector_type(4), may_alias)) float f32x4a;
typedef __attribute__((may_alias)) float floata;

#define DEV static __device__ __forceinline__

DEV unsigned short f2bf(float f) {
  unsigned int u = __builtin_bit_cast(unsigned int, f);
  u += 0x7fffu + ((u >> 16) & 1u);   // RNE
  return (unsigned short)(u >> 16);
}

DEV float exp2_(float x) {
#if __has_builtin(__builtin_amdgcn_exp2f)
  return __builtin_amdgcn_exp2f(x);
#else
  float r; asm("v_exp_f32 %0, %1" : "=v"(r) : "v"(x)); return r;
#endif
}

DEV unsigned int cvtpk_bf16(float lo, float hi) {
  unsigned int r;
  asm("v_cvt_pk_bf16_f32 %0, %1, %2" : "=v"(r) : "v"(lo), "v"(hi));
  return r;
}

DEV void g2lds16(const void* g, void* l) {
  __builtin_amdgcn_global_load_lds((const __attribute__((address_space(1))) void*)g,
                                   (__attribute__((address_space(3))) void*)l, 16, 0, 0);
}

// ---------- input conversion: all_hs = concat(hidden, encoder) -> bf16 ----------
__global__ __launch_bounds__(256) void convert_allhs(const float* __restrict__ hid,
                                                     const float* __restrict__ enc,
                                                     unsigned short* __restrict__ ah) {
  int idx = blockIdx.x * 256 + threadIdx.x;
  const int perB = 4096 * 256;
  int b = idx / perB, r = idx - b * perB;
  int s = r >> 8, c4 = r & 255;
  const float* srcrow = (s < 2048) ? hid + (size_t)(b * 2048 + s) * 1024
                                   : enc + (size_t)(b * 2048 + (s - 2048)) * 1024;
  f32x4 v = *(const f32x4*)(srcrow + c4 * 4);
  us4 o;
  o[0] = f2bf(v[0]); o[1] = f2bf(v[1]); o[2] = f2bf(v[2]); o[3] = f2bf(v[3]);
  *(us4*)(ah + (size_t)idx * 4) = o;
}

// ---------- mask premultiply by log2(e) ----------
__global__ __launch_bounds__(256) void premul_mask(const float* __restrict__ m,
                                                   float* __restrict__ o) {
  int i = blockIdx.x * 256 + threadIdx.x;
  o[i] = m[i] * 1.4426950408889634f;
}

// ---------- merged weight transpose: Wt[n][k] = bf16(W[k][n]) for Wq,Wk,Wv ----------
__global__ __launch_bounds__(256) void transpose_w3(const float* __restrict__ Wq,
                                                    const float* __restrict__ Wk,
                                                    const float* __restrict__ Wv,
                                                    unsigned short* __restrict__ WtBase) {
  __shared__ unsigned short t[64][65];
  const int z = blockIdx.z;
  const float* W = (z == 0) ? Wq : (z == 1) ? Wk : Wv;
  unsigned short* Wt = WtBase + (size_t)z * 1048576;
  int k0 = blockIdx.y * 64, n0 = blockIdx.x * 64;
  int tid = threadIdx.x;
#pragma unroll
  for (int rep = 0; rep < 16; rep++) {
    int idx = rep * 256 + tid;
    int kk = idx >> 6, nn = idx & 63;
    t[kk][nn] = f2bf(W[(size_t)(k0 + kk) * 1024 + n0 + nn]);
  }
  __syncthreads();
#pragma unroll
  for (int rep = 0; rep < 16; rep++) {
    int idx = rep * 256 + tid;
    int nn = idx >> 6, kk = idx & 63;
    Wt[(size_t)(n0 + nn) * 1024 + k0 + kk] = t[kk][nn];
  }
}

// ---------- merged NT GEMM: Q + K + V projections in ONE 1280-block dispatch ----------
__global__ __launch_bounds__(256) void gemm_all(const unsigned short* __restrict__ WTQ,
                                                const unsigned short* __restrict__ WTK,
                                                const unsigned short* __restrict__ WTV,
                                                const unsigned short* __restrict__ AH,
                                                const float* __restrict__ bq,
                                                const float* __restrict__ bk,
                                                const float* __restrict__ bv,
                                                unsigned short* __restrict__ Qout,
                                                unsigned short* __restrict__ Kout,
                                                unsigned short* __restrict__ Vout,
                                                float qscale) {
  __shared__ unsigned short ldsA[128 * 32];
  __shared__ unsigned short ldsB[128 * 32];

  int id = blockIdx.x;
  int f2 = (id & 7) * 160 + (id >> 3);

  const unsigned short *A, *Bm;
  const float* bias;
  unsigned short* outb;
  int S, mode, r0, c0;
  float osc = 1.0f;
  if (f2 < 256) {                       // Q
    int t = f2;
    int b = t >> 7; t &= 127;
    c0 = (t & 15) * 128; r0 = (t >> 4) * 128;
    A = WTQ; Bm = AH + (size_t)b * 4194304; bias = bq;
    outb = Qout + (size_t)b * 2097152; S = 2048; mode = 0; osc = qscale;
  } else if (f2 < 768) {                // K
    int t = f2 - 256;
    int b = t >> 8; t &= 255;
    c0 = (t & 31) * 128; r0 = (t >> 5) * 128;
    A = WTK; Bm = AH + (size_t)b * 4194304; bias = bk;
    outb = Kout + (size_t)b * 4194304; S = 4096; mode = 0;
  } else {                              // V (transposed out)
    int t = f2 - 768;
    int b = t >> 8; t &= 255;
    c0 = (t & 7) * 128; r0 = (t >> 3) * 128;
    A = AH + (size_t)b * 4194304; Bm = WTV; bias = bv;
    outb = Vout + (size_t)b * 4194304; S = 4096; mode = 1;
  }

  const int tid = threadIdx.x, w = tid >> 6, l = tid & 63;
  const int wr = w >> 1, wc = w & 1;
  const int lrow = l >> 2, lk = (l & 3) * 8;
  const int lc = l & 15, g = l >> 4;

  f32x4 acc[4][4];
#pragma unroll
  for (int i = 0; i < 4; i++)
#pragma unroll
    for (int j = 0; j < 4; j++) acc[i][j] = (f32x4){0.f, 0.f, 0.f, 0.f};

  for (int k0 = 0; k0 < 1024; k0 += 32) {
#pragma unroll
    for (int t = 0; t < 2; t++) {
      const int tt = w * 2 + t;
      g2lds16(A + (size_t)(r0 + tt * 16 + lrow) * 1024 + k0 + lk, (char*)ldsA + tt * 1024);
      g2lds16(Bm + (size_t)(c0 + tt * 16 + lrow) * 1024 + k0 + lk, (char*)ldsB + tt * 1024);
    }
    __syncthreads();
    short8 af[4], bf[4];
#pragma unroll
    for (int f = 0; f < 4; f++) {
      af[f] = *(const short8*)((const char*)ldsA + (wr * 64 + f * 16 + lc) * 64 + g * 16);
      bf[f] = *(const short8*)((const char*)ldsB + (wc * 64 + f * 16 + lc) * 64 + g * 16);
    }
#pragma unroll
    for (int fr = 0; fr < 4; fr++)
#pragma unroll
      for (int fc = 0; fc < 4; fc++)
        acc[fr][fc] = __builtin_amdgcn_mfma_f32_16x16x32_bf16(af[fr], bf[fc], acc[fr][fc], 0, 0, 0);
    __syncthreads();
  }

#pragma unroll
  for (int fr = 0; fr < 4; fr++) {
    int rb = r0 + wr * 64 + fr * 16 + g * 4;
    float bv4[4];
    if (mode == 0) {
#pragma unroll
      for (int i = 0; i < 4; i++) bv4[i] = bias[rb + i];
    }
#pragma unroll
    for (int fc = 0; fc < 4; fc++) {
      int c = c0 + wc * 64 + fc * 16 + lc;
      float bc = (mode == 0) ? 0.f : bias[c];
      us4 pk;
#pragma unroll
      for (int i = 0; i < 4; i++) {
        float v = (acc[fr][fc][i] + (mode == 0 ? bv4[i] : bc)) * osc;
        pk[i] = f2bf(v);
      }
      size_t addr;
      if (mode == 0) addr = ((size_t)(rb >> 6) * S + c) * 64 + (rb & 63);
      else           addr = (size_t)c * S + rb;
      *(us4*)(outb + addr) = pk;
    }
  }
}

// ---------- flash attention v13: mfma_32x32x16 + permlane P redistribution (fixed) ----------
// Q[b][h][sq][d] (pre-scaled by 0.125*log2e), K[b][h][skv][d], Vt[b][h][d][skv] (bf16);
// mask2 = mask*log2e fp32; out fp32 [B][SQ][H].
// Block: 4 waves = 2 rg (32 q-rows each) x 2 kh (2048 kv each). Tile = 64 kv, 32 iters.
// S^T = mfma_32x32x16(K, Q): lane (h2=l>>5, lq=l&31) holds P[q=lq][kv=(r&3)+4h2+8(r>>2)].
//
// permlane32_swap semantics (CDNA4): swap(D,S): new_D = concat(D_lo, S_lo);
// new_S = concat(D_hi, S_hi). (D keeps lanes<32, gains S's lanes<32 into lanes>=32;
// S gains D's lanes>=32 into lanes<32, keeps its lanes>=32.)
// R12 BUG: operands reversed + outputs crosswise -> every fragment misrouted (absmax .29).
// Correct: for PV B-frag words (j-pairs), with X[br]=cvtpk(p[4br],p[4br+1]),
// Y[br]=cvtpk(p[4br+2],p[4br+3]):
//   w0 = concat(X[2k2]_lo, X[2k2+1]_lo) = new_D of swap(D=X[2k2], S=X[2k2+1])
//   w2 = concat(X[2k2]_hi, X[2k2+1]_hi) = new_S of same
//   w1/w3 likewise with Y. P never touches LDS.
// ls is a per-lane f32 sum, cross-half folded ONCE at the end (shfl_xor 32).
// LDS = K[2kh][64][128B] + V[2kh][64][128B] = 32KB; reg-staged prefetch (masks first).
__global__ __launch_bounds__(256) void attn_kernel(const unsigned short* __restrict__ Q,
                                                   const unsigned short* __restrict__ K,
                                                   const unsigned short* __restrict__ Vt,
                                                   const float* __restrict__ mask2,
                                                   float* __restrict__ out) {
  __shared__ __align__(16) char lds[32768];
  // [0,16384): K tiles, kh*8192, [64 kv][128B] XOR-swizzled (slot j holds chunk j^(kv&7))
  // [16384,32768): V tiles, kh*8192, [64 d][128B] XOR-swizzled (slot j holds chunk j^(d&7))

  // XCD-chunked swizzle (T1)
  int flat = blockIdx.x + 32 * (blockIdx.y + 16 * blockIdx.z);   // 0..1023
  int xc = flat & 7, tt = flat >> 3;
  int f2 = xc * 64 + (tt & 63) + (tt >> 6) * 512;
  const int qt = f2 & 31, h = (f2 >> 5) & 15, b = f2 >> 9;

  const int tid = threadIdx.x, w = tid >> 6, l = tid & 63;
  const int rg = w & 1, kh = w >> 1;
  const int lq = l & 31, h2 = l >> 5;

  const unsigned short* Qb = Q + ((size_t)(b * 16 + h) * 2048) * 64;
  const unsigned short* Kb = K + ((size_t)((b * 16 + h) * 4096 + kh * 2048)) * 64;
  const unsigned short* Vb = Vt + ((size_t)(b * 16 + h) * 64) * 4096 + kh * 2048;
  const float* mk = mask2 + (size_t)b * 4096 + kh * 2048;
  const int sq0 = qt * 64 + rg * 32;

  char* kbase = lds + kh * 8192;
  char* vbase = lds + 16384 + kh * 8192;

  // staging geometry: 4 calls/lane, call c covers 8 rows x 8 slots; lane -> row+(l>>3), slot l&7
  const int srow8 = l >> 3, slot = l & 7;

  // Q fragments: B-operand of 32x32x16: lane holds q=lq, d = ks*16 + h2*8 + j
  short8 qf[4];
#pragma unroll
  for (int ks = 0; ks < 4; ks++)
    qf[ks] = *(const short8*)(Qb + (size_t)(sq0 + lq) * 64 + ks * 16 + h2 * 8);

  f32x16 ctx[2];
#pragma unroll
  for (int d = 0; d < 2; d++)
#pragma unroll
    for (int r = 0; r < 16; r++) ctx[d][r] = 0.f;
  float lsr = 0.f;

  // ---- stage tile 0 via regs ----
  {
    short8 kreg[4], vreg[4];
#pragma unroll
    for (int c = 0; c < 4; c++) {
      int kr = rg * 32 + c * 8 + srow8;
      kreg[c] = *(const short8*)(Kb + (size_t)kr * 64 + (slot ^ (kr & 7)) * 8);
      vreg[c] = *(const short8*)(Vb + (size_t)kr * 4096 + (slot ^ (kr & 7)) * 8);
    }
#pragma unroll
    for (int c = 0; c < 4; c++) {
      int kr = rg * 32 + c * 8 + srow8;
      *(short8a*)(kbase + kr * 128 + slot * 16) = kreg[c];
      *(short8a*)(vbase + kr * 128 + slot * 16) = vreg[c];
    }
  }
  __syncthreads();

  for (int t = 0; t < 32; t++) {
    const int s0 = t * 64;

    // mask loads FIRST (oldest vmcnt slots; waiting them leaves prefetch in flight)
    f32x4 mv[2][4];
#pragma unroll
    for (int sub = 0; sub < 2; sub++)
#pragma unroll
      for (int br = 0; br < 4; br++)
        mv[sub][br] = *(const f32x4*)(mk + s0 + sub * 32 + br * 8 + h2 * 4);

    // reg-prefetch tile t+1
    short8 kreg[4], vreg[4];
    if (t < 31) {
#pragma unroll
      for (int c = 0; c < 4; c++) {
        int kr = rg * 32 + c * 8 + srow8;
        kreg[c] = *(const short8*)(Kb + (size_t)(s0 + 64 + kr) * 64 + (slot ^ (kr & 7)) * 8);
        vreg[c] = *(const short8*)(Vb + (size_t)kr * 4096 + (s0 + 64) + (slot ^ (kr & 7)) * 8);
      }
    }

    // ---- QK^T per 32-kv sub; P in registers via cvtpk + permlane32_swap ----
    short8 bfr[2][2];   // [sub][k2] PV B-fragments
#pragma unroll
    for (int sub = 0; sub < 2; sub++) {
      f32x16 z;
#pragma unroll
      for (int br = 0; br < 4; br++)
#pragma unroll
        for (int i = 0; i < 4; i++) z[br * 4 + i] = mv[sub][br][i];
#pragma unroll
      for (int ks = 0; ks < 4; ks++) {
        short8 kf = *(const short8*)(kbase + (sub * 32 + lq) * 128 + (((ks * 2 + h2) ^ (lq & 7)) << 4));
        z = __builtin_amdgcn_mfma_f32_32x32x16_bf16(kf, qf[ks], z, 0, 0, 0);
      }
      float p[16];
#pragma unroll
      for (int r = 0; r < 16; r++) { p[r] = exp2_(z[r]); lsr += p[r]; }
      unsigned int X[4], Y[4];
#pragma unroll
      for (int br = 0; br < 4; br++) {
        X[br] = cvtpk_bf16(p[br * 4 + 0], p[br * 4 + 1]);
        Y[br] = cvtpk_bf16(p[br * 4 + 2], p[br * 4 + 3]);
      }
#pragma unroll
      for (int k2 = 0; k2 < 2; k2++) {
        // CORRECTED: D = lower-kv word X[2k2], S = upper-kv word X[2k2+1];
        // after swap: D' = w0 (j0,j1), S' = w2 (j4,j5). Same for Y -> w1, w3.
        unsigned int xd = X[2 * k2], xs = X[2 * k2 + 1];
        asm("v_permlane32_swap_b32 %0, %1" : "+v"(xd), "+v"(xs));
        unsigned int yd = Y[2 * k2], ys = Y[2 * k2 + 1];
        asm("v_permlane32_swap_b32 %0, %1" : "+v"(yd), "+v"(ys));
        u32x4 packed = (u32x4){xd, yd, xs, ys};
        bfr[sub][k2] = __builtin_bit_cast(short8, packed);
      }
    }

    // ---- PV: ctx[dsub] += mfma(V-frag, P-frag) ----
#pragma unroll
    for (int dsub = 0; dsub < 2; dsub++)
#pragma unroll
      for (int sub = 0; sub < 2; sub++)
#pragma unroll
        for (int k2 = 0; k2 < 2; k2++) {
          short8 vf = *(const short8*)(vbase + (dsub * 32 + lq) * 128 +
                                       (((sub * 4 + k2 * 2 + h2) ^ (lq & 7)) << 4));
          ctx[dsub] = __builtin_amdgcn_mfma_f32_32x32x16_bf16(vf, bfr[sub][k2], ctx[dsub], 0, 0, 0);
        }

    __syncthreads();   // all waves done reading LDS tile t

    if (t < 31) {
#pragma unroll
      for (int c = 0; c < 4; c++) {
        int kr = rg * 32 + c * 8 + srow8;
        *(short8a*)(kbase + kr * 128 + slot * 16) = kreg[c];
        *(short8a*)(vbase + kr * 128 + slot * 16) = vreg[c];
      }
      __syncthreads();
    }
  }

  // fold cross-half ls once (h2 halves own complementary kv rows)
  float ls_tot = lsr + __shfl_xor(lsr, 32, 64);

  // ---- merge kh halves (raw sums under no-max softmax) ----
  float* mC = (float*)lds;            // [64 q][16 slots of 16B], slot = (d>>2) ^ (q&15)
  float* lB = (float*)(lds + 16384);  // 64 floats
  const int q = rg * 32 + lq;
  if (kh == 1) {
#pragma unroll
    for (int dsub = 0; dsub < 2; dsub++)
#pragma unroll
      for (int br = 0; br < 4; br++) {
        int d0 = dsub * 32 + br * 8 + h2 * 4;
        f32x4 v = (f32x4){ctx[dsub][br * 4 + 0], ctx[dsub][br * 4 + 1],
                          ctx[dsub][br * 4 + 2], ctx[dsub][br * 4 + 3]};
        *(f32x4a*)((char*)mC + q * 256 + (((d0 >> 2) ^ (q & 15)) << 4)) = v;
      }
    if (h2 == 0) *(floata*)(lB + q) = ls_tot;
  }
  __syncthreads();
  if (kh == 0) {
    float inv = 1.f / (ls_tot + *(const floata*)(lB + q));
    size_t orow = (size_t)(b * 2048 + qt * 64 + q);
#pragma unroll
    for (int dsub = 0; dsub < 2; dsub++)
#pragma unroll
      for (int br = 0; br < 4; br++) {
        int d0 = dsub * 32 + br * 8 + h2 * 4;
        f32x4 other = *(const f32x4a*)((char*)mC + q * 256 + (((d0 >> 2) ^ (q & 15)) << 4));
        f32x4 own = (f32x4){ctx[dsub][br * 4 + 0], ctx[dsub][br * 4 + 1],
                            ctx[dsub][br * 4 + 2], ctx[dsub][br * 4 + 3]};
        f32x4 o = (own + other) * inv;
        *(f32x4*)(out + orow * 1024 + h * 64 + d0) = o;
      }
  }
}

// ---------- launcher ----------
extern "C" void kernel_launch(void* const* d_in, const int* in_sizes, int n_in,
                              void* d_out, int out_size, void* d_ws, size_t ws_size,
                              hipStream_t stream) {
  const float* hid = (const float*)d_in[0];
  const float* enc = (const float*)d_in[1];
  const float* mask = (const float*)d_in[2];
  const float* Wq = (const float*)d_in[3];
  const float* bq = (const float*)d_in[4];
  const float* Wk = (const float*)d_in[5];
  const float* bk = (const float*)d_in[6];
  const float* Wv = (const float*)d_in[7];
  const float* bv = (const float*)d_in[8];

  unsigned short* ws = (unsigned short*)d_ws;
  unsigned short* WTQ = ws;                    // 1M elems (WTQ/WTK/WTV contiguous)
  unsigned short* WTK = ws + 1048576;          // 1M
  unsigned short* WTV = ws + 2097152;          // 1M
  unsigned short* AH  = ws + 3145728;          // 8M  [B][4096][1024]
  unsigned short* Qb  = ws + 11534336;         // 4M  [B][16][2048][64]
  unsigned short* Kb  = ws + 15728640;         // 8M  [B][16][4096][64]
  unsigned short* VT  = ws + 24117248;         // 8M  [B][16][64][4096]
  float* mask2 = (float*)(ws + 32505856);      // 8192 fp32

  const float QSCALE = 0.18033688011112042f;   // 0.125 * log2(e), folded into Q projection

  convert_allhs<<<8192, 256, 0, stream>>>(hid, enc, AH);
  premul_mask<<<32, 256, 0, stream>>>(mask, mask2);
  transpose_w3<<<dim3(16, 16, 3), 256, 0, stream>>>(Wq, Wk, Wv, WTQ);

  gemm_all<<<1280, 256, 0, stream>>>(WTQ, WTK, WTV, AH, bq, bk, bv, Qb, Kb, VT, QSCALE);

  attn_kernel<<<dim3(32, 16, 2), 256, 0, stream>>>(Qb, Kb, VT, mask2, (float*)d_out);
}